// Round 1
// baseline (5635.294 us; speedup 1.0000x reference)
//
#include <hip/hip_runtime.h>

// Qwen2.5-VL vision tower forward, MI355X gfx950.
// All inputs f32; GEMMs run bf16-MFMA (16x16x32) with f32 accumulation.
// Workspace layout (f32): x[2.048M] h[2.048M] qkv[6.144M] o[2.048M]
//                         g[5.472M] u[5.472M] t1[2.048M]  = 101.1 MB.

typedef __bf16 bf16x8 __attribute__((ext_vector_type(8)));
typedef float  f32x4  __attribute__((ext_vector_type(4)));

#define DEV __device__ __forceinline__

DEV unsigned short f2bf(float f) {            // RNE f32 -> bf16 bits
    union { float f; unsigned u; } v; v.f = f;
    unsigned r = v.u + 0x7FFFu + ((v.u >> 16) & 1u);
    return (unsigned short)(r >> 16);
}

enum { EPI_NONE = 0, EPI_BIAS = 1, EPI_BIAS_RESID = 2, EPI_BIAS_GELU = 3 };

// out(RxC) = A(RxK) @ B(CxK)^T [+bias] [+resid] [gelu]; all f32 in memory.
template <int EPI>
__global__ __launch_bounds__(256, 2)
void gemm_kernel(const float* __restrict__ A, const float* __restrict__ B,
                 const float* __restrict__ bias, const float* __restrict__ resid,
                 float* __restrict__ out, int R, int C, int K)
{
    __shared__ __align__(16) unsigned short As[128][40];  // 32 k + pad(40 => 80B rows, 16B-aligned, 2-way max)
    __shared__ __align__(16) unsigned short Bs[128][40];
    const int tid  = threadIdx.x;
    const int lane = tid & 63;
    const int wave = tid >> 6;
    const int r0 = blockIdx.y * 128;
    const int c0 = blockIdx.x * 128;
    const int wr = (wave >> 1) * 64;
    const int wc = (wave & 1) * 64;
    const int l15 = lane & 15;
    const int kk  = (lane >> 4) * 8;

    f32x4 acc[4][4];
#pragma unroll
    for (int i = 0; i < 4; ++i)
#pragma unroll
        for (int j = 0; j < 4; ++j) acc[i][j] = (f32x4){0.f, 0.f, 0.f, 0.f};

    for (int k0 = 0; k0 < K; k0 += 32) {
#pragma unroll
        for (int i = 0; i < 4; ++i) {            // 1024 quads per tile, 4/thread
            int qid = tid + 256 * i;
            int row = qid >> 3;
            int kq  = (qid & 7) * 4;
            int gk  = k0 + kq;
            float4 va = make_float4(0.f, 0.f, 0.f, 0.f);
            int gr = r0 + row;
            if (gr < R && gk < K) va = *reinterpret_cast<const float4*>(&A[(size_t)gr * K + gk]);
            unsigned p0 = (unsigned)f2bf(va.x) | ((unsigned)f2bf(va.y) << 16);
            unsigned p1 = (unsigned)f2bf(va.z) | ((unsigned)f2bf(va.w) << 16);
            *reinterpret_cast<uint2*>(&As[row][kq]) = make_uint2(p0, p1);
            float4 vb = make_float4(0.f, 0.f, 0.f, 0.f);
            int gc = c0 + row;
            if (gc < C && gk < K) vb = *reinterpret_cast<const float4*>(&B[(size_t)gc * K + gk]);
            p0 = (unsigned)f2bf(vb.x) | ((unsigned)f2bf(vb.y) << 16);
            p1 = (unsigned)f2bf(vb.z) | ((unsigned)f2bf(vb.w) << 16);
            *reinterpret_cast<uint2*>(&Bs[row][kq]) = make_uint2(p0, p1);
        }
        __syncthreads();
        bf16x8 af[4], bfr[4];
#pragma unroll
        for (int f = 0; f < 4; ++f) {
            af[f]  = *reinterpret_cast<const bf16x8*>(&As[wr + f * 16 + l15][kk]);
            bfr[f] = *reinterpret_cast<const bf16x8*>(&Bs[wc + f * 16 + l15][kk]);
        }
#pragma unroll
        for (int fr = 0; fr < 4; ++fr)
#pragma unroll
            for (int fc = 0; fc < 4; ++fc)
                acc[fr][fc] = __builtin_amdgcn_mfma_f32_16x16x32_bf16(af[fr], bfr[fc], acc[fr][fc], 0, 0, 0);
        __syncthreads();
    }

    const int rowb = r0 + wr + (lane >> 4) * 4;
    const int colb = c0 + wc + l15;
#pragma unroll
    for (int fc = 0; fc < 4; ++fc) {
        int col = colb + fc * 16;
        if (col >= C) continue;
        float bv = (EPI != EPI_NONE) ? bias[col] : 0.f;
#pragma unroll
        for (int fr = 0; fr < 4; ++fr) {
#pragma unroll
            for (int r2 = 0; r2 < 4; ++r2) {
                int row = rowb + fr * 16 + r2;
                if (row >= R) continue;
                float v = acc[fr][fc][r2] + bv;
                if (EPI == EPI_BIAS_RESID) v += resid[(size_t)row * C + col];
                if (EPI == EPI_BIAS_GELU)  v = 0.5f * v * (1.f + erff(v * 0.70710678118f));
                out[(size_t)row * C + col] = v;
            }
        }
    }
}

__global__ void rms_kernel(const float* __restrict__ x, const float* __restrict__ w,
                           float* __restrict__ out, int cols)
{
    const int row = blockIdx.x;
    const int tid = threadIdx.x;
    const float* xr = x + (size_t)row * cols;
    float ss = 0.f;
    for (int c = tid; c < cols; c += 256) { float v = xr[c]; ss += v * v; }
#pragma unroll
    for (int m = 1; m < 64; m <<= 1) ss += __shfl_xor(ss, m);
    __shared__ float wsum[4];
    if ((tid & 63) == 0) wsum[tid >> 6] = ss;
    __syncthreads();
    float tot = wsum[0] + wsum[1] + wsum[2] + wsum[3];
    float rs = rsqrtf(tot / (float)cols + 1e-6f);
    float* orow = out + (size_t)row * cols;
    for (int c = tid; c < cols; c += 256) orow[c] = xr[c] * rs * w[c];
}

// In-place RoPE on q and k halves of qkv (f32). 1600*16*40 threads exact.
__global__ void rope_kernel(float* __restrict__ qkv, const float* __restrict__ cosb,
                            const float* __restrict__ sinb)
{
    int idx = blockIdx.x * 256 + threadIdx.x;   // < 1,024,000
    int n   = idx / 640;
    int rem = idx - n * 640;
    int hh  = rem / 40;
    int d   = rem - hh * 40;
    float c0 = cosb[n * 80 + d];
    float s0 = sinb[n * 80 + d];
    float c1 = cosb[n * 80 + d + 40];
    float s1 = sinb[n * 80 + d + 40];
    size_t base = (size_t)n * 3840 + hh * 80;
    float a = qkv[base + d], b = qkv[base + d + 40];
    qkv[base + d]      = a * c0 - b * s0;
    qkv[base + d + 40] = b * c1 + a * s1;
    base += 1280;
    a = qkv[base + d]; b = qkv[base + d + 40];
    qkv[base + d]      = a * c0 - b * s0;
    qkv[base + d + 40] = b * c1 + a * s1;
}

__global__ void silu_mul_kernel(float* __restrict__ g, const float* __restrict__ u, int n)
{
    int idx = blockIdx.x * 256 + threadIdx.x;
    if (idx < n) {
        float gv = g[idx], uv = u[idx];
        g[idx] = gv / (1.f + expf(-gv)) * uv;
    }
}

// Flash attention: block = 4 waves, 64 q-rows, one head; 25 chunks of 64 keys.
// QK^T and PV via mfma_f32_16x16x32_bf16; softmax in-register (row spread over
// a 16-lane group, shfl_xor 1/2/4/8 row-reduce); P through per-wave LDS.
__global__ __launch_bounds__(256, 2)
void attn_kernel(const float* __restrict__ qkv, float* __restrict__ o)
{
    __shared__ __align__(16) unsigned short Klds[64][104];   // d-slots 0..95 (80..95 zero)
    __shared__ __align__(16) unsigned short Vt[80][72];      // transposed: [d][key]
    __shared__ __align__(16) unsigned short Plds[4][16][72]; // per-wave P 16x64
    const int tid  = threadIdx.x;
    const int lane = tid & 63;
    const int w    = tid >> 6;
    const int l15  = lane & 15;
    const int kk   = (lane >> 4) * 8;
    const int qt   = blockIdx.x;   // 0..24
    const int hh   = blockIdx.y;   // 0..15
    const float scale = 0.11180339887498949f;  // 80^-0.5 folded into Q

    const int qrow = qt * 64 + w * 16 + l15;
    bf16x8 aq[3];
#pragma unroll
    for (int s = 0; s < 3; ++s) {
        int d = 32 * s + kk;
        union { bf16x8 v; unsigned short us[8]; } uu;
        if (d < 80) {
            const float* qp = &qkv[(size_t)qrow * 3840 + hh * 80 + d];
            float4 v0 = *reinterpret_cast<const float4*>(qp);
            float4 v1 = *reinterpret_cast<const float4*>(qp + 4);
            uu.us[0] = f2bf(v0.x * scale); uu.us[1] = f2bf(v0.y * scale);
            uu.us[2] = f2bf(v0.z * scale); uu.us[3] = f2bf(v0.w * scale);
            uu.us[4] = f2bf(v1.x * scale); uu.us[5] = f2bf(v1.y * scale);
            uu.us[6] = f2bf(v1.z * scale); uu.us[7] = f2bf(v1.w * scale);
        } else {
#pragma unroll
            for (int j = 0; j < 8; ++j) uu.us[j] = 0;
        }
        aq[s] = uu.v;
    }

    f32x4 acc_o[5];
#pragma unroll
    for (int fd = 0; fd < 5; ++fd) acc_o[fd] = (f32x4){0.f, 0.f, 0.f, 0.f};
    float m[4], lsum[4];
#pragma unroll
    for (int r2 = 0; r2 < 4; ++r2) { m[r2] = -__builtin_inff(); lsum[r2] = 0.f; }

    const int koff = 1280 + hh * 80;
    const int voff = 2560 + hh * 80;

    for (int kb = 0; kb < 25; ++kb) {
#pragma unroll
        for (int i = 0; i < 6; ++i) {           // K tile: 64 x 24 quads (last 4 zero-pad)
            int qi = tid + 256 * i;             // 0..1535
            int r  = qi / 24;
            int c4 = (qi - r * 24) * 4;
            uint2 pk = make_uint2(0u, 0u);
            if (c4 < 80) {
                float4 v = *reinterpret_cast<const float4*>(&qkv[(size_t)(kb * 64 + r) * 3840 + koff + c4]);
                pk.x = (unsigned)f2bf(v.x) | ((unsigned)f2bf(v.y) << 16);
                pk.y = (unsigned)f2bf(v.z) | ((unsigned)f2bf(v.w) << 16);
            }
            *reinterpret_cast<uint2*>(&Klds[r][c4]) = pk;
        }
#pragma unroll
        for (int i = 0; i < 5; ++i) {           // V tile transposed: 64 x 20 quads
            int qi = tid + 256 * i;             // 0..1279
            int r  = qi / 20;
            int c4 = (qi - r * 20) * 4;
            float4 v = *reinterpret_cast<const float4*>(&qkv[(size_t)(kb * 64 + r) * 3840 + voff + c4]);
            Vt[c4 + 0][r] = f2bf(v.x);
            Vt[c4 + 1][r] = f2bf(v.y);
            Vt[c4 + 2][r] = f2bf(v.z);
            Vt[c4 + 3][r] = f2bf(v.w);
        }
        __syncthreads();

        f32x4 sf[4];
#pragma unroll
        for (int fc = 0; fc < 4; ++fc) {
            f32x4 c = (f32x4){0.f, 0.f, 0.f, 0.f};
#pragma unroll
            for (int s = 0; s < 3; ++s)
                c = __builtin_amdgcn_mfma_f32_16x16x32_bf16(
                        aq[s],
                        *reinterpret_cast<const bf16x8*>(&Klds[fc * 16 + l15][32 * s + kk]),
                        c, 0, 0, 0);
            sf[fc] = c;
        }

        float mx[4];
#pragma unroll
        for (int r2 = 0; r2 < 4; ++r2)
            mx[r2] = fmaxf(fmaxf(sf[0][r2], sf[1][r2]), fmaxf(sf[2][r2], sf[3][r2]));
#pragma unroll
        for (int msk = 1; msk <= 8; msk <<= 1)
#pragma unroll
            for (int r2 = 0; r2 < 4; ++r2)
                mx[r2] = fmaxf(mx[r2], __shfl_xor(mx[r2], msk));
        float alpha[4];
#pragma unroll
        for (int r2 = 0; r2 < 4; ++r2) {
            float mn = fmaxf(m[r2], mx[r2]);
            alpha[r2] = expf(m[r2] - mn);
            m[r2] = mn;
        }
        float psum[4] = {0.f, 0.f, 0.f, 0.f};
#pragma unroll
        for (int fc = 0; fc < 4; ++fc)
#pragma unroll
            for (int r2 = 0; r2 < 4; ++r2) {
                float p = expf(sf[fc][r2] - m[r2]);
                sf[fc][r2] = p;
                psum[r2] += p;
            }
#pragma unroll
        for (int msk = 1; msk <= 8; msk <<= 1)
#pragma unroll
            for (int r2 = 0; r2 < 4; ++r2) psum[r2] += __shfl_xor(psum[r2], msk);
#pragma unroll
        for (int r2 = 0; r2 < 4; ++r2) lsum[r2] = lsum[r2] * alpha[r2] + psum[r2];
#pragma unroll
        for (int fd = 0; fd < 5; ++fd)
#pragma unroll
            for (int r2 = 0; r2 < 4; ++r2) acc_o[fd][r2] *= alpha[r2];

        const int prow = (lane >> 4) * 4;
#pragma unroll
        for (int fc = 0; fc < 4; ++fc)
#pragma unroll
            for (int r2 = 0; r2 < 4; ++r2)
                Plds[w][prow + r2][fc * 16 + l15] = f2bf(sf[fc][r2]);

        bf16x8 ap[2];
#pragma unroll
        for (int ks = 0; ks < 2; ++ks)
            ap[ks] = *reinterpret_cast<const bf16x8*>(&Plds[w][l15][32 * ks + kk]);
#pragma unroll
        for (int fd = 0; fd < 5; ++fd)
#pragma unroll
            for (int ks = 0; ks < 2; ++ks)
                acc_o[fd] = __builtin_amdgcn_mfma_f32_16x16x32_bf16(
                        ap[ks],
                        *reinterpret_cast<const bf16x8*>(&Vt[fd * 16 + l15][32 * ks + kk]),
                        acc_o[fd], 0, 0, 0);
        __syncthreads();
    }

    float inv[4];
#pragma unroll
    for (int r2 = 0; r2 < 4; ++r2) inv[r2] = 1.f / lsum[r2];
    const int orow = qt * 64 + w * 16 + (lane >> 4) * 4;
    const int ocol = hh * 80 + l15;
#pragma unroll
    for (int fd = 0; fd < 5; ++fd)
#pragma unroll
        for (int r2 = 0; r2 < 4; ++r2)
            o[(size_t)(orow + r2) * 1280 + ocol + fd * 16] = acc_o[fd][r2] * inv[r2];
}

extern "C" void kernel_launch(void* const* d_in, const int* in_sizes, int n_in,
                              void* d_out, int out_size, void* d_ws, size_t ws_size,
                              hipStream_t stream)
{
    const float* pixel  = (const float*)d_in[0];
    const float* cosb   = (const float*)d_in[1];
    const float* sinb   = (const float*)d_in[2];
    const float* patchw = (const float*)d_in[3];
    const float* n1w    = (const float*)d_in[4];
    const float* qkvw   = (const float*)d_in[5];
    const float* qkvb   = (const float*)d_in[6];
    const float* projw  = (const float*)d_in[7];
    const float* projb  = (const float*)d_in[8];
    const float* n2w    = (const float*)d_in[9];
    const float* gatew  = (const float*)d_in[10];
    const float* gateb  = (const float*)d_in[11];
    const float* upw    = (const float*)d_in[12];
    const float* upb    = (const float*)d_in[13];
    const float* downw  = (const float*)d_in[14];
    const float* downb  = (const float*)d_in[15];
    const float* lnqw   = (const float*)d_in[16];
    const float* m1w    = (const float*)d_in[17];
    const float* m1b    = (const float*)d_in[18];
    const float* m2w    = (const float*)d_in[19];
    const float* m2b    = (const float*)d_in[20];
    float* out = (float*)d_out;

    float* x   = (float*)d_ws;
    float* h   = x   + 2048000;
    float* qkv = h   + 2048000;
    float* o   = qkv + 6144000;
    float* g   = o   + 2048000;
    float* u   = g   + 5472000;
    float* t1  = u   + 5472000;

    dim3 blk(256);
    gemm_kernel<EPI_NONE><<<dim3(10, 13), blk, 0, stream>>>(pixel, patchw, nullptr, nullptr, x, 1600, 1280, 1176);
    for (int i = 0; i < 4; ++i) {
        rms_kernel<<<1600, blk, 0, stream>>>(x, n1w + i * 1280, h, 1280);
        gemm_kernel<EPI_BIAS><<<dim3(30, 13), blk, 0, stream>>>(h, qkvw + (size_t)i * 3840 * 1280, qkvb + i * 3840, nullptr, qkv, 1600, 3840, 1280);
        rope_kernel<<<4000, blk, 0, stream>>>(qkv, cosb, sinb);
        attn_kernel<<<dim3(25, 16), blk, 0, stream>>>(qkv, o);
        gemm_kernel<EPI_BIAS_RESID><<<dim3(10, 13), blk, 0, stream>>>(o, projw + (size_t)i * 1280 * 1280, projb + i * 1280, x, x, 1600, 1280, 1280);
        rms_kernel<<<1600, blk, 0, stream>>>(x, n2w + i * 1280, h, 1280);
        gemm_kernel<EPI_BIAS><<<dim3(27, 13), blk, 0, stream>>>(h, gatew + (size_t)i * 3420 * 1280, gateb + i * 3420, nullptr, g, 1600, 3420, 1280);
        gemm_kernel<EPI_BIAS><<<dim3(27, 13), blk, 0, stream>>>(h, upw + (size_t)i * 3420 * 1280, upb + i * 3420, nullptr, u, 1600, 3420, 1280);
        silu_mul_kernel<<<21375, blk, 0, stream>>>(g, u, 5472000);
        gemm_kernel<EPI_BIAS_RESID><<<dim3(10, 13), blk, 0, stream>>>(g, downw + (size_t)i * 1280 * 3420, downb + i * 1280, x, x, 1600, 1280, 3420);
    }
    rms_kernel<<<1600, blk, 0, stream>>>(x, lnqw, h, 1280);
    gemm_kernel<EPI_BIAS_GELU><<<dim3(40, 4), blk, 0, stream>>>(h, m1w, m1b, nullptr, t1, 400, 5120, 5120);
    gemm_kernel<EPI_BIAS><<<dim3(28, 4), blk, 0, stream>>>(t1, m2w, m2b, nullptr, out, 400, 3584, 5120);
}

// Round 2
// 1999.719 us; speedup vs baseline: 2.8180x; 2.8180x over previous
//
#include <hip/hip_runtime.h>

// Qwen2.5-VL vision tower forward, MI355X gfx950 — round 1.
// Strategy: pre-convert weights/pixels to bf16 (padded to 128/32 multiples),
// all GEMMs run a 2-phase double-buffered global_load_lds(16B) pipeline with
// mfma_f32_16x16x32_bf16; activations flow as bf16; residual x stays f32.

typedef __bf16 bf16x8 __attribute__((ext_vector_type(8)));
typedef float  f32x4  __attribute__((ext_vector_type(4)));
typedef unsigned short u16;

#define DEV __device__ __forceinline__

DEV u16 f2bf(float f) {                       // RNE f32 -> bf16 bits
    union { float f; unsigned u; } v; v.f = f;
    unsigned r = v.u + 0x7FFFu + ((v.u >> 16) & 1u);
    return (u16)(r >> 16);
}
DEV float bf2f(u16 b) {
    union { float f; unsigned u; } v; v.u = ((unsigned)b) << 16; return v.f;
}

DEV void gload16(const u16* g, u16* l) {      // async global->LDS, 16B/lane
    __builtin_amdgcn_global_load_lds(
        (const __attribute__((address_space(1))) unsigned int*)g,
        (__attribute__((address_space(3))) unsigned int*)l, 16, 0, 0);
}

enum { EPI_NONE = 0, EPI_BIAS = 1, EPI_BIAS_RESID = 2, EPI_BIAS_GELU = 3 };

// f32 -> bf16 convert with zero-padding; blockIdx.y = layer.
__global__ void cvt_kernel(const float* __restrict__ src, u16* __restrict__ dst,
                           int Rs, int Cs, int Rp, int Cp,
                           long long sls, long long dls)
{
    const float* s = src + (size_t)blockIdx.y * sls;
    u16* d = dst + (size_t)blockIdx.y * dls;
    int idx = blockIdx.x * 256 + threadIdx.x;
    int cpc = Cp >> 3;
    if (idx >= Rp * cpc) return;
    int row = idx / cpc;
    int c0  = (idx - row * cpc) * 8;
    u16 v[8];
    if (row < Rs && c0 + 8 <= Cs) {
        float4 a = *reinterpret_cast<const float4*>(&s[(size_t)row * Cs + c0]);
        float4 b = *reinterpret_cast<const float4*>(&s[(size_t)row * Cs + c0 + 4]);
        v[0] = f2bf(a.x); v[1] = f2bf(a.y); v[2] = f2bf(a.z); v[3] = f2bf(a.w);
        v[4] = f2bf(b.x); v[5] = f2bf(b.y); v[6] = f2bf(b.z); v[7] = f2bf(b.w);
    } else {
#pragma unroll
        for (int j = 0; j < 8; ++j) {
            int c = c0 + j;
            v[j] = (row < Rs && c < Cs) ? f2bf(s[(size_t)row * Cs + c]) : (u16)0;
        }
    }
    *reinterpret_cast<uint4*>(&d[(size_t)row * Cp + c0]) =
        *reinterpret_cast<const uint4*>(v);
}

DEV void stage_tile(const u16* __restrict__ A, const u16* __restrict__ B,
                    u16* sa, u16* sb, int r0, int c0, int Kp, int k0, int cA0)
{
#pragma unroll
    for (int j = 0; j < 2; ++j) {
        int c = cA0 + j * 64;
        int row = c >> 2, cb = (c & 3) * 8;
        gload16(&A[(size_t)(r0 + row) * Kp + k0 + cb], &sa[c * 8]);
        gload16(&B[(size_t)(c0 + row) * Kp + k0 + cb], &sb[c * 8]);
    }
}

// out(RxC) = A(RxKp) @ B(CxKp)^T, bf16 in, epilogue per EPI. Grid covers
// padded R,C exactly (128-multiples); row write-guard Rlim, col zero >= Creal.
template <int EPI, bool OF32>
__global__ __launch_bounds__(256, 2)
void gemm16_kernel(const u16* __restrict__ A, const u16* __restrict__ B,
                   const float* __restrict__ bias, const float* __restrict__ resid,
                   void* __restrict__ outp, int Kp, int ldc, int Creal, int Rlim)
{
    __shared__ u16 sA[2][4096];
    __shared__ u16 sB[2][4096];
    const int tid  = threadIdx.x;
    const int lane = tid & 63;
    const int w    = tid >> 6;
    const int r0 = blockIdx.y * 128;
    const int c0 = blockIdx.x * 128;
    const int wr = (w >> 1) * 64;
    const int wc = (w & 1) * 64;
    const int l15 = lane & 15;
    const int kk  = (lane >> 4) * 8;
    const int cA0 = w * 128 + lane;

    f32x4 acc[4][4];
#pragma unroll
    for (int i = 0; i < 4; ++i)
#pragma unroll
        for (int j = 0; j < 4; ++j) acc[i][j] = (f32x4){0.f, 0.f, 0.f, 0.f};

    const int NT = Kp >> 5;
    stage_tile(A, B, &sA[0][0], &sB[0][0], r0, c0, Kp, 0, cA0);
    __syncthreads();
    int buf = 0;
    for (int kt = 0; kt < NT; ++kt) {
        if (kt + 1 < NT)
            stage_tile(A, B, &sA[buf ^ 1][0], &sB[buf ^ 1][0], r0, c0, Kp,
                       (kt + 1) * 32, cA0);
        bf16x8 af[4], bfr[4];
#pragma unroll
        for (int f = 0; f < 4; ++f) {
            af[f]  = *reinterpret_cast<const bf16x8*>(&sA[buf][(wr + f * 16 + l15) * 32 + kk]);
            bfr[f] = *reinterpret_cast<const bf16x8*>(&sB[buf][(wc + f * 16 + l15) * 32 + kk]);
        }
#pragma unroll
        for (int fr = 0; fr < 4; ++fr)
#pragma unroll
            for (int fc = 0; fc < 4; ++fc)
                acc[fr][fc] = __builtin_amdgcn_mfma_f32_16x16x32_bf16(af[fr], bfr[fc], acc[fr][fc], 0, 0, 0);
        __syncthreads();
        buf ^= 1;
    }

    const int rowb = r0 + wr + (lane >> 4) * 4;
    const int colb = c0 + wc + l15;
#pragma unroll
    for (int fc = 0; fc < 4; ++fc) {
        int col = colb + fc * 16;
        float bv = (EPI != EPI_NONE && col < Creal) ? bias[col] : 0.f;
#pragma unroll
        for (int fr = 0; fr < 4; ++fr) {
#pragma unroll
            for (int r2 = 0; r2 < 4; ++r2) {
                int row = rowb + fr * 16 + r2;
                if (row >= Rlim) continue;
                float v = acc[fr][fc][r2] + bv;
                if (col >= Creal) v = 0.f;
                if (EPI == EPI_BIAS_RESID) v += resid[(size_t)row * ldc + col];
                if (EPI == EPI_BIAS_GELU)  v = 0.5f * v * (1.f + erff(v * 0.70710678118f));
                if (OF32) ((float*)outp)[(size_t)row * ldc + col] = v;
                else      ((u16*)outp)[(size_t)row * ldc + col] = f2bf(v);
            }
        }
    }
}

__global__ void rms_kernel(const float* __restrict__ x, const float* __restrict__ w,
                           u16* __restrict__ out, int cols)
{
    const int row = blockIdx.x;
    const int tid = threadIdx.x;
    const float* xr = x + (size_t)row * cols;
    float ss = 0.f;
    for (int c = tid; c < cols; c += 256) { float v = xr[c]; ss += v * v; }
#pragma unroll
    for (int m = 1; m < 64; m <<= 1) ss += __shfl_xor(ss, m);
    __shared__ float wsum[4];
    if ((tid & 63) == 0) wsum[tid >> 6] = ss;
    __syncthreads();
    float tot = wsum[0] + wsum[1] + wsum[2] + wsum[3];
    float rs = rsqrtf(tot / (float)cols + 1e-6f);
    u16* orow = out + (size_t)row * cols;
    for (int c = tid; c < cols; c += 256) orow[c] = f2bf(xr[c] * rs * w[c]);
}

// In-place RoPE on bf16 q,k halves of qkv.
__global__ void rope_kernel(u16* __restrict__ qkv, const float* __restrict__ cosb,
                            const float* __restrict__ sinb)
{
    int idx = blockIdx.x * 256 + threadIdx.x;   // < 1,024,000
    int n   = idx / 640;
    int rem = idx - n * 640;
    int hh  = rem / 40;
    int d   = rem - hh * 40;
    float c0 = cosb[n * 80 + d];
    float s0 = sinb[n * 80 + d];
    float c1 = cosb[n * 80 + d + 40];
    float s1 = sinb[n * 80 + d + 40];
    size_t base = (size_t)n * 3840 + hh * 80;
    float a = bf2f(qkv[base + d]), b = bf2f(qkv[base + d + 40]);
    qkv[base + d]      = f2bf(a * c0 - b * s0);
    qkv[base + d + 40] = f2bf(b * c1 + a * s1);
    base += 1280;
    a = bf2f(qkv[base + d]); b = bf2f(qkv[base + d + 40]);
    qkv[base + d]      = f2bf(a * c0 - b * s0);
    qkv[base + d + 40] = f2bf(b * c1 + a * s1);
}

__global__ void silu_mul_kernel(u16* __restrict__ g, const u16* __restrict__ u, int n8)
{
    int idx = blockIdx.x * 256 + threadIdx.x;
    if (idx >= n8) return;
    u16 gv[8], uv[8];
    *reinterpret_cast<uint4*>(gv) = *reinterpret_cast<const uint4*>(&g[(size_t)idx * 8]);
    *reinterpret_cast<uint4*>(uv) = *reinterpret_cast<const uint4*>(&u[(size_t)idx * 8]);
#pragma unroll
    for (int j = 0; j < 8; ++j) {
        float x = bf2f(gv[j]);
        gv[j] = f2bf(x / (1.f + expf(-x)) * bf2f(uv[j]));
    }
    *reinterpret_cast<uint4*>(&g[(size_t)idx * 8]) = *reinterpret_cast<const uint4*>(gv);
}

// Flash attention on bf16 qkv (post-rope): block = 4 waves, 64 q-rows, 1 head.
__global__ __launch_bounds__(256, 2)
void attn_kernel(const u16* __restrict__ qkv, u16* __restrict__ o)
{
    __shared__ __align__(16) u16 Klds[64][104];
    __shared__ __align__(16) u16 Vt[80][72];
    __shared__ __align__(16) u16 Plds[4][16][72];
    const int tid  = threadIdx.x;
    const int lane = tid & 63;
    const int w    = tid >> 6;
    const int l15  = lane & 15;
    const int kk   = (lane >> 4) * 8;
    const int qt   = blockIdx.x;
    const int hh   = blockIdx.y;
    const float scale = 0.11180339887498949f;

    const int qrow = qt * 64 + w * 16 + l15;
    bf16x8 aq[3];
#pragma unroll
    for (int s = 0; s < 3; ++s) {
        int d = 32 * s + kk;
        union { bf16x8 v; uint4 q; u16 us[8]; } uu;
        if (d < 80) uu.q = *reinterpret_cast<const uint4*>(&qkv[(size_t)qrow * 3840 + hh * 80 + d]);
        else        uu.q = (uint4){0u, 0u, 0u, 0u};
        aq[s] = uu.v;
    }

    f32x4 acc_o[5];
#pragma unroll
    for (int fd = 0; fd < 5; ++fd) acc_o[fd] = (f32x4){0.f, 0.f, 0.f, 0.f};
    float m[4], lsum[4];
#pragma unroll
    for (int r2 = 0; r2 < 4; ++r2) { m[r2] = -__builtin_inff(); lsum[r2] = 0.f; }

    const int koff = 1280 + hh * 80;
    const int voff = 2560 + hh * 80;

    for (int kb = 0; kb < 25; ++kb) {
#pragma unroll
        for (int i = 0; i < 3; ++i) {             // K tile: 64 rows x 12 chunks
            int c = tid + 256 * i;                // 0..767
            int r = c / 12, c8 = (c - r * 12) * 8;
            uint4 pk = (uint4){0u, 0u, 0u, 0u};
            if (c8 < 80)
                pk = *reinterpret_cast<const uint4*>(&qkv[(size_t)(kb * 64 + r) * 3840 + koff + c8]);
            *reinterpret_cast<uint4*>(&Klds[r][c8]) = pk;
        }
#pragma unroll
        for (int i = 0; i < 3; ++i) {             // V tile transposed: 640 chunks
            int c = tid + 256 * i;
            if (c < 640) {
                int r = c / 10, c8 = (c - r * 10) * 8;
                u16 v[8];
                *reinterpret_cast<uint4*>(v) =
                    *reinterpret_cast<const uint4*>(&qkv[(size_t)(kb * 64 + r) * 3840 + voff + c8]);
#pragma unroll
                for (int j = 0; j < 8; ++j) Vt[c8 + j][r] = v[j];
            }
        }
        __syncthreads();

        f32x4 sf[4];
#pragma unroll
        for (int fc = 0; fc < 4; ++fc) {
            f32x4 c = (f32x4){0.f, 0.f, 0.f, 0.f};
#pragma unroll
            for (int s = 0; s < 3; ++s)
                c = __builtin_amdgcn_mfma_f32_16x16x32_bf16(
                        aq[s],
                        *reinterpret_cast<const bf16x8*>(&Klds[fc * 16 + l15][32 * s + kk]),
                        c, 0, 0, 0);
            sf[fc] = c * scale;
        }

        float mx[4];
#pragma unroll
        for (int r2 = 0; r2 < 4; ++r2)
            mx[r2] = fmaxf(fmaxf(sf[0][r2], sf[1][r2]), fmaxf(sf[2][r2], sf[3][r2]));
#pragma unroll
        for (int msk = 1; msk <= 8; msk <<= 1)
#pragma unroll
            for (int r2 = 0; r2 < 4; ++r2)
                mx[r2] = fmaxf(mx[r2], __shfl_xor(mx[r2], msk));
        float alpha[4];
#pragma unroll
        for (int r2 = 0; r2 < 4; ++r2) {
            float mn = fmaxf(m[r2], mx[r2]);
            alpha[r2] = expf(m[r2] - mn);
            m[r2] = mn;
        }
        float psum[4] = {0.f, 0.f, 0.f, 0.f};
#pragma unroll
        for (int fc = 0; fc < 4; ++fc)
#pragma unroll
            for (int r2 = 0; r2 < 4; ++r2) {
                float p = expf(sf[fc][r2] - m[r2]);
                sf[fc][r2] = p;
                psum[r2] += p;
            }
#pragma unroll
        for (int msk = 1; msk <= 8; msk <<= 1)
#pragma unroll
            for (int r2 = 0; r2 < 4; ++r2) psum[r2] += __shfl_xor(psum[r2], msk);
#pragma unroll
        for (int r2 = 0; r2 < 4; ++r2) lsum[r2] = lsum[r2] * alpha[r2] + psum[r2];
#pragma unroll
        for (int fd = 0; fd < 5; ++fd)
#pragma unroll
            for (int r2 = 0; r2 < 4; ++r2) acc_o[fd][r2] *= alpha[r2];

        const int prow = (lane >> 4) * 4;
#pragma unroll
        for (int fc = 0; fc < 4; ++fc)
#pragma unroll
            for (int r2 = 0; r2 < 4; ++r2)
                Plds[w][prow + r2][fc * 16 + l15] = f2bf(sf[fc][r2]);

        bf16x8 ap[2];
#pragma unroll
        for (int ks = 0; ks < 2; ++ks)
            ap[ks] = *reinterpret_cast<const bf16x8*>(&Plds[w][l15][32 * ks + kk]);
#pragma unroll
        for (int fd = 0; fd < 5; ++fd)
#pragma unroll
            for (int ks = 0; ks < 2; ++ks)
                acc_o[fd] = __builtin_amdgcn_mfma_f32_16x16x32_bf16(
                        ap[ks],
                        *reinterpret_cast<const bf16x8*>(&Vt[fd * 16 + l15][32 * ks + kk]),
                        acc_o[fd], 0, 0, 0);
        __syncthreads();
    }

    float inv[4];
#pragma unroll
    for (int r2 = 0; r2 < 4; ++r2) inv[r2] = 1.f / lsum[r2];
    const int orow = qt * 64 + w * 16 + (lane >> 4) * 4;
    const int ocol = hh * 80 + l15;
#pragma unroll
    for (int fd = 0; fd < 5; ++fd)
#pragma unroll
        for (int r2 = 0; r2 < 4; ++r2)
            o[(size_t)(orow + r2) * 1280 + ocol + fd * 16] = f2bf(acc_o[fd][r2] * inv[r2]);
}

extern "C" void kernel_launch(void* const* d_in, const int* in_sizes, int n_in,
                              void* d_out, int out_size, void* d_ws, size_t ws_size,
                              hipStream_t stream)
{
    const float* pixel  = (const float*)d_in[0];
    const float* cosb   = (const float*)d_in[1];
    const float* sinb   = (const float*)d_in[2];
    const float* patchw = (const float*)d_in[3];
    const float* n1w    = (const float*)d_in[4];
    const float* qkvw   = (const float*)d_in[5];
    const float* qkvb   = (const float*)d_in[6];
    const float* projw  = (const float*)d_in[7];
    const float* projb  = (const float*)d_in[8];
    const float* n2w    = (const float*)d_in[9];
    const float* gatew  = (const float*)d_in[10];
    const float* gateb  = (const float*)d_in[11];
    const float* upw    = (const float*)d_in[12];
    const float* upb    = (const float*)d_in[13];
    const float* downw  = (const float*)d_in[14];
    const float* downb  = (const float*)d_in[15];
    const float* lnqw   = (const float*)d_in[16];
    const float* m1w    = (const float*)d_in[17];
    const float* m1b    = (const float*)d_in[18];
    const float* m2w    = (const float*)d_in[19];
    const float* m2b    = (const float*)d_in[20];
    float* out = (float*)d_out;

    char* base = (char*)d_ws;
    float* x      = (float*)(base);                    // 1664x1280 f32
    u16*   h      = (u16*)(base + 8519680);            // 512x5120 view / 1664x1280
    u16*   qbuf   = (u16*)(base + 13762560);           // 1664x3840
    u16*   o      = (u16*)(base + 26542080);           // 1664x1280
    u16*   g      = (u16*)(base + 30801920);           // 1664x3456
    u16*   u      = (u16*)(base + 42303488);           // 1664x3456
    u16*   t1     = (u16*)(base + 53805056);           // 512x5120
    u16*   pix16  = (u16*)(base + 59047936);           // 1664x1184
    u16*   pw16   = (u16*)(base + 62988288);           // 1280x1184
    u16*   qkvw16 = (u16*)(base + 66019328);           // 4x3840x1280
    u16*   projw16= (u16*)(base + 105340928);          // 4x1280x1280
    u16*   mlpw16 = (u16*)(base + 118448128);          // 106.2MB region
    u16*   gatew16= mlpw16;                            // 4x3456x1280
    u16*   upw16  = mlpw16 + 17694720;                 // elems
    u16*   downw16= mlpw16 + 35389440;                 // 4x1280x3456
    u16*   m1w16  = mlpw16;                            // alias (after layer loop)
    u16*   m2w16  = mlpw16 + 26214400;                 // elems

    dim3 blk(256);
    auto cvb = [](int Rp, int Cp) { return (Rp * (Cp >> 3) + 255) / 256; };

    cvt_kernel<<<dim3(cvb(1664,1184),1), blk, 0, stream>>>(pixel, pix16, 1600, 1176, 1664, 1184, 0, 0);
    cvt_kernel<<<dim3(cvb(1280,1184),1), blk, 0, stream>>>(patchw, pw16, 1280, 1176, 1280, 1184, 0, 0);
    cvt_kernel<<<dim3(cvb(15360,1280),1), blk, 0, stream>>>(qkvw, qkvw16, 15360, 1280, 15360, 1280, 0, 0);
    cvt_kernel<<<dim3(cvb(5120,1280),1), blk, 0, stream>>>(projw, projw16, 5120, 1280, 5120, 1280, 0, 0);
    cvt_kernel<<<dim3(cvb(3456,1280),4), blk, 0, stream>>>(gatew, gatew16, 3420, 1280, 3456, 1280, 4377600LL, 4423680LL);
    cvt_kernel<<<dim3(cvb(3456,1280),4), blk, 0, stream>>>(upw, upw16, 3420, 1280, 3456, 1280, 4377600LL, 4423680LL);
    cvt_kernel<<<dim3(cvb(1280,3456),4), blk, 0, stream>>>(downw, downw16, 1280, 3420, 1280, 3456, 4377600LL, 4423680LL);

    gemm16_kernel<EPI_NONE, true><<<dim3(10,13), blk, 0, stream>>>(pix16, pw16, nullptr, nullptr, x, 1184, 1280, 1280, 1664);
    for (int i = 0; i < 4; ++i) {
        rms_kernel<<<1600, blk, 0, stream>>>(x, n1w + i*1280, h, 1280);
        gemm16_kernel<EPI_BIAS, false><<<dim3(30,13), blk, 0, stream>>>(h, qkvw16 + (size_t)i*4915200, qkvb + i*3840, nullptr, qbuf, 1280, 3840, 3840, 1664);
        rope_kernel<<<4000, blk, 0, stream>>>(qbuf, cosb, sinb);
        attn_kernel<<<dim3(25,16), blk, 0, stream>>>(qbuf, o);
        gemm16_kernel<EPI_BIAS_RESID, true><<<dim3(10,13), blk, 0, stream>>>(o, projw16 + (size_t)i*1638400, projb + i*1280, x, x, 1280, 1280, 1280, 1664);
        rms_kernel<<<1600, blk, 0, stream>>>(x, n2w + i*1280, h, 1280);
        gemm16_kernel<EPI_BIAS, false><<<dim3(27,13), blk, 0, stream>>>(h, gatew16 + (size_t)i*4423680, gateb + i*3420, nullptr, g, 1280, 3456, 3420, 1664);
        gemm16_kernel<EPI_BIAS, false><<<dim3(27,13), blk, 0, stream>>>(h, upw16 + (size_t)i*4423680, upb + i*3420, nullptr, u, 1280, 3456, 3420, 1664);
        silu_mul_kernel<<<2808, blk, 0, stream>>>(g, u, 718848);
        gemm16_kernel<EPI_BIAS_RESID, true><<<dim3(10,13), blk, 0, stream>>>(g, downw16 + (size_t)i*4423680, downb + i*1280, x, x, 3456, 1280, 1280, 1664);
    }
    cvt_kernel<<<dim3(cvb(5120,5120),1), blk, 0, stream>>>(m1w, m1w16, 5120, 5120, 5120, 5120, 0, 0);
    cvt_kernel<<<dim3(cvb(3584,5120),1), blk, 0, stream>>>(m2w, m2w16, 3584, 5120, 3584, 5120, 0, 0);
    rms_kernel<<<1600, blk, 0, stream>>>(x, lnqw, h, 1280);
    gemm16_kernel<EPI_BIAS_GELU, false><<<dim3(40,4), blk, 0, stream>>>(h, m1w16, m1b, nullptr, t1, 5120, 5120, 5120, 512);
    gemm16_kernel<EPI_BIAS, true><<<dim3(28,4), blk, 0, stream>>>(t1, m2w16, m2b, nullptr, out, 5120, 3584, 3584, 400);
}

// Round 3
// 1800.270 us; speedup vs baseline: 3.1303x; 1.1108x over previous
//
#include <hip/hip_runtime.h>

// Qwen2.5-VL vision tower forward, MI355X gfx950 — round 2.
// GEMM: 128x128 tile, BK=32, ring-3 LDS prefetch with counted vmcnt + raw
// s_barrier (T4), XCD-chunked block swizzle (T1, m204 bijective), gate+up
// fused into one GEMM. Weights pre-converted to padded bf16 each launch.

typedef __bf16 bf16x8 __attribute__((ext_vector_type(8)));
typedef float  f32x4  __attribute__((ext_vector_type(4)));
typedef unsigned short u16;

#define DEV __device__ __forceinline__

DEV u16 f2bf(float f) {                       // RNE f32 -> bf16 bits
    union { float f; unsigned u; } v; v.f = f;
    unsigned r = v.u + 0x7FFFu + ((v.u >> 16) & 1u);
    return (u16)(r >> 16);
}
DEV float bf2f(u16 b) {
    union { float f; unsigned u; } v; v.u = ((unsigned)b) << 16; return v.f;
}

DEV void gload16(const u16* g, u16* l) {      // async global->LDS, 16B/lane
    __builtin_amdgcn_global_load_lds(
        (const __attribute__((address_space(1))) unsigned int*)g,
        (__attribute__((address_space(3))) unsigned int*)l, 16, 0, 0);
}

enum { EPI_NONE = 0, EPI_BIAS = 1, EPI_BIAS_RESID = 2, EPI_BIAS_GELU = 3 };

// f32 -> bf16 convert with zero-padding; blockIdx.y = layer.
__global__ void cvt_kernel(const float* __restrict__ src, u16* __restrict__ dst,
                           int Rs, int Cs, int Rp, int Cp,
                           long long sls, long long dls)
{
    const float* s = src + (size_t)blockIdx.y * sls;
    u16* d = dst + (size_t)blockIdx.y * dls;
    int idx = blockIdx.x * 256 + threadIdx.x;
    int cpc = Cp >> 3;
    if (idx >= Rp * cpc) return;
    int row = idx / cpc;
    int c0  = (idx - row * cpc) * 8;
    u16 v[8];
    if (row < Rs && c0 + 8 <= Cs) {
        float4 a = *reinterpret_cast<const float4*>(&s[(size_t)row * Cs + c0]);
        float4 b = *reinterpret_cast<const float4*>(&s[(size_t)row * Cs + c0 + 4]);
        v[0] = f2bf(a.x); v[1] = f2bf(a.y); v[2] = f2bf(a.z); v[3] = f2bf(a.w);
        v[4] = f2bf(b.x); v[5] = f2bf(b.y); v[6] = f2bf(b.z); v[7] = f2bf(b.w);
    } else {
#pragma unroll
        for (int j = 0; j < 8; ++j) {
            int c = c0 + j;
            v[j] = (row < Rs && c < Cs) ? f2bf(s[(size_t)row * Cs + c]) : (u16)0;
        }
    }
    *reinterpret_cast<uint4*>(&d[(size_t)row * Cp + c0]) =
        *reinterpret_cast<const uint4*>(v);
}

// Combined gate|up padded bias: [4][6912] f32.
__global__ void gub_kernel(const float* __restrict__ gb, const float* __restrict__ ub,
                           float* __restrict__ dst)
{
    int i = blockIdx.x * 256 + threadIdx.x;
    if (i >= 4 * 6912) return;
    int l = i / 6912, c = i - l * 6912;
    float v = 0.f;
    if (c < 3456) { if (c < 3420) v = gb[l * 3420 + c]; }
    else { int c2 = c - 3456; if (c2 < 3420) v = ub[l * 3420 + c2]; }
    dst[i] = v;
}

// out(RxC) = A(RxKp) @ B(CxKp)^T, bf16 in. Ring-3 LDS prefetch, counted vmcnt.
template <int EPI, bool OF32>
__global__ __launch_bounds__(256, 3)
void gemm16_kernel(const u16* __restrict__ A, const u16* __restrict__ B,
                   const float* __restrict__ bias, const float* __restrict__ resid,
                   void* __restrict__ outp, int Kp, int ldc, int Rlim)
{
    __shared__ u16 sA[3][4096];
    __shared__ u16 sB[3][4096];
    const int tid  = threadIdx.x;
    const int lane = tid & 63;
    const int w    = tid >> 6;

    // bijective XCD-chunked swizzle (m204), column-major linearization
    unsigned gy  = gridDim.y;
    unsigned nwg = gridDim.x * gy;
    unsigned lin = blockIdx.x * gy + blockIdx.y;
    unsigned q = nwg >> 3, r = nwg & 7, xc = lin & 7, off = lin >> 3;
    unsigned id2 = (xc < r ? xc * (q + 1) : r * (q + 1) + (xc - r) * q) + off;
    const int c0 = (int)(id2 / gy) * 128;
    const int r0 = (int)(id2 - (id2 / gy) * gy) * 128;

    const int wr  = (w >> 1) * 64;
    const int wc  = (w & 1) * 64;
    const int l15 = lane & 15;
    const int kk  = (lane >> 4) * 8;
    const int ca  = w * 128 + lane;                 // 16B-chunk ids ca, ca+64
    const size_t arow0 = (size_t)(r0 + (ca >> 2)) * Kp + (ca & 3) * 8;
    const size_t brow0 = (size_t)(c0 + (ca >> 2)) * Kp + (ca & 3) * 8;
    const size_t arow1 = (size_t)(r0 + ((ca + 64) >> 2)) * Kp + ((ca + 64) & 3) * 8;
    const size_t brow1 = (size_t)(c0 + ((ca + 64) >> 2)) * Kp + ((ca + 64) & 3) * 8;

    f32x4 acc[4][4];
#pragma unroll
    for (int i = 0; i < 4; ++i)
#pragma unroll
        for (int j = 0; j < 4; ++j) acc[i][j] = (f32x4){0.f, 0.f, 0.f, 0.f};

    auto stage = [&](int kt, int buf) {
        int k0 = kt * 32;
        gload16(A + arow0 + k0, &sA[buf][ca * 8]);
        gload16(B + brow0 + k0, &sB[buf][ca * 8]);
        gload16(A + arow1 + k0, &sA[buf][(ca + 64) * 8]);
        gload16(B + brow1 + k0, &sB[buf][(ca + 64) * 8]);
    };
    auto compute = [&](int buf) {
        bf16x8 af[4], bfr[4];
#pragma unroll
        for (int f = 0; f < 4; ++f) {
            af[f]  = *reinterpret_cast<const bf16x8*>(&sA[buf][(wr + f * 16 + l15) * 32 + kk]);
            bfr[f] = *reinterpret_cast<const bf16x8*>(&sB[buf][(wc + f * 16 + l15) * 32 + kk]);
        }
#pragma unroll
        for (int fr = 0; fr < 4; ++fr)
#pragma unroll
            for (int fc = 0; fc < 4; ++fc)
                acc[fr][fc] = __builtin_amdgcn_mfma_f32_16x16x32_bf16(af[fr], bfr[fc], acc[fr][fc], 0, 0, 0);
    };

    const int NT = Kp >> 5;
    stage(0, 0);
    if (NT > 1) stage(1, 1);
    int bcur = 0;
    for (int t = 0; t < NT - 1; ++t) {
        asm volatile("s_waitcnt vmcnt(4)" ::: "memory");
        __builtin_amdgcn_s_barrier();
        __builtin_amdgcn_sched_barrier(0);
        if (t + 2 < NT) {
            int bn = bcur + 2; if (bn >= 3) bn -= 3;
            stage(t + 2, bn);
        }
        __builtin_amdgcn_sched_barrier(0);
        compute(bcur);
        bcur = (bcur == 2) ? 0 : bcur + 1;
    }
    asm volatile("s_waitcnt vmcnt(0)" ::: "memory");
    __builtin_amdgcn_s_barrier();
    __builtin_amdgcn_sched_barrier(0);
    compute(bcur);

    const int rowb = r0 + wr + (lane >> 4) * 4;
    const int colb = c0 + wc + l15;
#pragma unroll
    for (int fc = 0; fc < 4; ++fc) {
        int col = colb + fc * 16;
        float bv = (EPI != EPI_NONE) ? bias[col] : 0.f;
#pragma unroll
        for (int fr = 0; fr < 4; ++fr) {
#pragma unroll
            for (int r2 = 0; r2 < 4; ++r2) {
                int row = rowb + fr * 16 + r2;
                if (row >= Rlim) continue;
                float v = acc[fr][fc][r2] + bv;
                if (EPI == EPI_BIAS_RESID) v += resid[(size_t)row * ldc + col];
                if (EPI == EPI_BIAS_GELU)  v = 0.5f * v * (1.f + erff(v * 0.70710678118f));
                if (OF32) ((float*)outp)[(size_t)row * ldc + col] = v;
                else      ((u16*)outp)[(size_t)row * ldc + col] = f2bf(v);
            }
        }
    }
}

__global__ void rms_kernel(const float* __restrict__ x, const float* __restrict__ w,
                           u16* __restrict__ out, int cols)
{
    const int row = blockIdx.x;
    const int tid = threadIdx.x;
    const float* xr = x + (size_t)row * cols;
    float ss = 0.f;
    for (int c = tid; c < cols; c += 256) { float v = xr[c]; ss += v * v; }
#pragma unroll
    for (int m = 1; m < 64; m <<= 1) ss += __shfl_xor(ss, m);
    __shared__ float wsum[4];
    if ((tid & 63) == 0) wsum[tid >> 6] = ss;
    __syncthreads();
    float tot = wsum[0] + wsum[1] + wsum[2] + wsum[3];
    float rs = rsqrtf(tot / (float)cols + 1e-6f);
    u16* orow = out + (size_t)row * cols;
    for (int c = tid; c < cols; c += 256) orow[c] = f2bf(xr[c] * rs * w[c]);
}

// In-place RoPE on bf16 q,k halves of qkv.
__global__ void rope_kernel(u16* __restrict__ qkv, const float* __restrict__ cosb,
                            const float* __restrict__ sinb)
{
    int idx = blockIdx.x * 256 + threadIdx.x;   // < 1,024,000
    int n   = idx / 640;
    int rem = idx - n * 640;
    int hh  = rem / 40;
    int d   = rem - hh * 40;
    float c0 = cosb[n * 80 + d];
    float s0 = sinb[n * 80 + d];
    float c1 = cosb[n * 80 + d + 40];
    float s1 = sinb[n * 80 + d + 40];
    size_t base = (size_t)n * 3840 + hh * 80;
    float a = bf2f(qkv[base + d]), b = bf2f(qkv[base + d + 40]);
    qkv[base + d]      = f2bf(a * c0 - b * s0);
    qkv[base + d + 40] = f2bf(b * c1 + a * s1);
    base += 1280;
    a = bf2f(qkv[base + d]); b = bf2f(qkv[base + d + 40]);
    qkv[base + d]      = f2bf(a * c0 - b * s0);
    qkv[base + d + 40] = f2bf(b * c1 + a * s1);
}

// silu(gate)*up from fused [1664][6912] buffer -> packed [1664][3456].
__global__ void silu_mul_kernel(const u16* __restrict__ gu, u16* __restrict__ outb)
{
    int idx = blockIdx.x * 256 + threadIdx.x;
    if (idx >= 1664 * 432) return;
    int row = idx / 432, c8 = (idx - row * 432) * 8;
    u16 gv[8], uv[8];
    *reinterpret_cast<uint4*>(gv) = *reinterpret_cast<const uint4*>(&gu[(size_t)row * 6912 + c8]);
    *reinterpret_cast<uint4*>(uv) = *reinterpret_cast<const uint4*>(&gu[(size_t)row * 6912 + 3456 + c8]);
#pragma unroll
    for (int j = 0; j < 8; ++j) {
        float x = bf2f(gv[j]);
        gv[j] = f2bf(x / (1.f + expf(-x)) * bf2f(uv[j]));
    }
    *reinterpret_cast<uint4*>(&outb[(size_t)row * 3456 + c8]) = *reinterpret_cast<const uint4*>(gv);
}

// Flash attention on bf16 qkv (post-rope): 4 waves, 64 q-rows, 1 head/block.
__global__ __launch_bounds__(256, 2)
void attn_kernel(const u16* __restrict__ qkv, u16* __restrict__ o)
{
    __shared__ __align__(16) u16 Klds[64][104];
    __shared__ __align__(16) u16 Vt[80][72];
    __shared__ __align__(16) u16 Plds[4][16][72];
    const int tid  = threadIdx.x;
    const int lane = tid & 63;
    const int w    = tid >> 6;
    const int l15  = lane & 15;
    const int kk   = (lane >> 4) * 8;
    // XCD-chunked swizzle: 2 heads per XCD chunk -> K/V L2 reuse
    unsigned lin = blockIdx.y * 25 + blockIdx.x;       // nwg=400, 400%8==0
    unsigned id2 = (lin & 7) * 50 + (lin >> 3);
    const int hh = (int)(id2 / 25);
    const int qt = (int)(id2 - hh * 25);
    const float scale = 0.11180339887498949f;

    const int qrow = qt * 64 + w * 16 + l15;
    bf16x8 aq[3];
#pragma unroll
    for (int s = 0; s < 3; ++s) {
        int d = 32 * s + kk;
        union { bf16x8 v; uint4 q; } uu;
        if (d < 80) uu.q = *reinterpret_cast<const uint4*>(&qkv[(size_t)qrow * 3840 + hh * 80 + d]);
        else        uu.q = (uint4){0u, 0u, 0u, 0u};
        aq[s] = uu.v;
    }

    f32x4 acc_o[5];
#pragma unroll
    for (int fd = 0; fd < 5; ++fd) acc_o[fd] = (f32x4){0.f, 0.f, 0.f, 0.f};
    float m[4], lsum[4];
#pragma unroll
    for (int r2 = 0; r2 < 4; ++r2) { m[r2] = -__builtin_inff(); lsum[r2] = 0.f; }

    const int koff = 1280 + hh * 80;
    const int voff = 2560 + hh * 80;

    for (int kb = 0; kb < 25; ++kb) {
#pragma unroll
        for (int i = 0; i < 3; ++i) {             // K tile: 64 rows x 12 chunks
            int c = tid + 256 * i;                // 0..767
            int r = c / 12, c8 = (c - r * 12) * 8;
            uint4 pk = (uint4){0u, 0u, 0u, 0u};
            if (c8 < 80)
                pk = *reinterpret_cast<const uint4*>(&qkv[(size_t)(kb * 64 + r) * 3840 + koff + c8]);
            *reinterpret_cast<uint4*>(&Klds[r][c8]) = pk;
        }
#pragma unroll
        for (int i = 0; i < 3; ++i) {             // V tile transposed: 640 chunks
            int c = tid + 256 * i;
            if (c < 640) {
                int r = c / 10, c8 = (c - r * 10) * 8;
                u16 v[8];
                *reinterpret_cast<uint4*>(v) =
                    *reinterpret_cast<const uint4*>(&qkv[(size_t)(kb * 64 + r) * 3840 + voff + c8]);
#pragma unroll
                for (int j = 0; j < 8; ++j) Vt[c8 + j][r] = v[j];
            }
        }
        __syncthreads();

        f32x4 sf[4];
#pragma unroll
        for (int fc = 0; fc < 4; ++fc) {
            f32x4 c = (f32x4){0.f, 0.f, 0.f, 0.f};
#pragma unroll
            for (int s = 0; s < 3; ++s)
                c = __builtin_amdgcn_mfma_f32_16x16x32_bf16(
                        aq[s],
                        *reinterpret_cast<const bf16x8*>(&Klds[fc * 16 + l15][32 * s + kk]),
                        c, 0, 0, 0);
            sf[fc] = c * scale;
        }

        float mx[4];
#pragma unroll
        for (int r2 = 0; r2 < 4; ++r2)
            mx[r2] = fmaxf(fmaxf(sf[0][r2], sf[1][r2]), fmaxf(sf[2][r2], sf[3][r2]));
#pragma unroll
        for (int msk = 1; msk <= 8; msk <<= 1)
#pragma unroll
            for (int r2 = 0; r2 < 4; ++r2)
                mx[r2] = fmaxf(mx[r2], __shfl_xor(mx[r2], msk));
        float alpha[4];
#pragma unroll
        for (int r2 = 0; r2 < 4; ++r2) {
            float mn = fmaxf(m[r2], mx[r2]);
            alpha[r2] = expf(m[r2] - mn);
            m[r2] = mn;
        }
        float psum[4] = {0.f, 0.f, 0.f, 0.f};
#pragma unroll
        for (int fc = 0; fc < 4; ++fc)
#pragma unroll
            for (int r2 = 0; r2 < 4; ++r2) {
                float p = expf(sf[fc][r2] - m[r2]);
                sf[fc][r2] = p;
                psum[r2] += p;
            }
#pragma unroll
        for (int msk = 1; msk <= 8; msk <<= 1)
#pragma unroll
            for (int r2 = 0; r2 < 4; ++r2) psum[r2] += __shfl_xor(psum[r2], msk);
#pragma unroll
        for (int r2 = 0; r2 < 4; ++r2) lsum[r2] = lsum[r2] * alpha[r2] + psum[r2];
#pragma unroll
        for (int fd = 0; fd < 5; ++fd)
#pragma unroll
            for (int r2 = 0; r2 < 4; ++r2) acc_o[fd][r2] *= alpha[r2];

        const int prow = (lane >> 4) * 4;
#pragma unroll
        for (int fc = 0; fc < 4; ++fc)
#pragma unroll
            for (int r2 = 0; r2 < 4; ++r2)
                Plds[w][prow + r2][fc * 16 + l15] = f2bf(sf[fc][r2]);

        bf16x8 ap[2];
#pragma unroll
        for (int ks = 0; ks < 2; ++ks)
            ap[ks] = *reinterpret_cast<const bf16x8*>(&Plds[w][l15][32 * ks + kk]);
#pragma unroll
        for (int fd = 0; fd < 5; ++fd)
#pragma unroll
            for (int ks = 0; ks < 2; ++ks)
                acc_o[fd] = __builtin_amdgcn_mfma_f32_16x16x32_bf16(
                        ap[ks],
                        *reinterpret_cast<const bf16x8*>(&Vt[fd * 16 + l15][32 * ks + kk]),
                        acc_o[fd], 0, 0, 0);
        __syncthreads();
    }

    float inv[4];
#pragma unroll
    for (int r2 = 0; r2 < 4; ++r2) inv[r2] = 1.f / lsum[r2];
    const int orow = qt * 64 + w * 16 + (lane >> 4) * 4;
    const int ocol = hh * 80 + l15;
#pragma unroll
    for (int fd = 0; fd < 5; ++fd)
#pragma unroll
        for (int r2 = 0; r2 < 4; ++r2)
            o[(size_t)(orow + r2) * 1280 + ocol + fd * 16] = f2bf(acc_o[fd][r2] * inv[r2]);
}

extern "C" void kernel_launch(void* const* d_in, const int* in_sizes, int n_in,
                              void* d_out, int out_size, void* d_ws, size_t ws_size,
                              hipStream_t stream)
{
    const float* pixel  = (const float*)d_in[0];
    const float* cosb   = (const float*)d_in[1];
    const float* sinb   = (const float*)d_in[2];
    const float* patchw = (const float*)d_in[3];
    const float* n1w    = (const float*)d_in[4];
    const float* qkvw   = (const float*)d_in[5];
    const float* qkvb   = (const float*)d_in[6];
    const float* projw  = (const float*)d_in[7];
    const float* projb  = (const float*)d_in[8];
    const float* n2w    = (const float*)d_in[9];
    const float* gatew  = (const float*)d_in[10];
    const float* gateb  = (const float*)d_in[11];
    const float* upw    = (const float*)d_in[12];
    const float* upb    = (const float*)d_in[13];
    const float* downw  = (const float*)d_in[14];
    const float* downb  = (const float*)d_in[15];
    const float* lnqw   = (const float*)d_in[16];
    const float* m1w    = (const float*)d_in[17];
    const float* m1b    = (const float*)d_in[18];
    const float* m2w    = (const float*)d_in[19];
    const float* m2b    = (const float*)d_in[20];
    float* out = (float*)d_out;

    char* base = (char*)d_ws;
    float* x      = (float*)(base);                       //  1664x1280 f32
    u16*   h      = (u16*)(base + 8519680);               //  1664x1280
    u16*   qbuf   = (u16*)(base + 12779520);              //  1664x3840
    u16*   pix16  = qbuf;                                 //  alias (pre-loop)
    u16*   gsep   = (u16*)(base + 25559040);              //  1664x3456
    u16*   o      = gsep;                                 //  alias (attn->proj)
    u16*   pw16   = gsep;                                 //  alias (pre-loop)
    u16*   gu     = (u16*)(base + 37060608);              //  1664x6912
    u16*   t1     = gu;                                   //  alias (post-loop, 512x5120)
    float* guB    = (float*)(base + 60063744);            //  4x6912 f32
    u16*   qkvw16 = (u16*)(base + 60174336);              //  4x3840x1280
    u16*   projw16= (u16*)(base + 99495936);              //  4x1280x1280
    u16*   guw16  = (u16*)(base + 112603136);             //  4x6912x1280
    u16*   downw16= (u16*)(base + 183382016);             //  4x1280x3456 (end 218.8MB)
    u16*   m1w16  = guw16;                                //  alias (post-loop)
    u16*   m2w16  = (u16*)(base + 112603136 + 52428800);  //  alias (post-loop)

    dim3 blk(256);
    auto cvb = [](int Rp, int Cp) { return (Rp * (Cp >> 3) + 255) / 256; };

    cvt_kernel<<<dim3(cvb(1664,1184),1), blk, 0, stream>>>(pixel, pix16, 1600, 1176, 1664, 1184, 0, 0);
    cvt_kernel<<<dim3(cvb(1280,1184),1), blk, 0, stream>>>(patchw, pw16, 1280, 1176, 1280, 1184, 0, 0);
    cvt_kernel<<<dim3(cvb(15360,1280),1), blk, 0, stream>>>(qkvw, qkvw16, 15360, 1280, 15360, 1280, 0, 0);
    cvt_kernel<<<dim3(cvb(5120,1280),1), blk, 0, stream>>>(projw, projw16, 5120, 1280, 5120, 1280, 0, 0);
    cvt_kernel<<<dim3(cvb(3456,1280),4), blk, 0, stream>>>(gatew, guw16, 3420, 1280, 3456, 1280, 4377600LL, 8847360LL);
    cvt_kernel<<<dim3(cvb(3456,1280),4), blk, 0, stream>>>(upw, guw16 + 4423680, 3420, 1280, 3456, 1280, 4377600LL, 8847360LL);
    cvt_kernel<<<dim3(cvb(1280,3456),4), blk, 0, stream>>>(downw, downw16, 1280, 3420, 1280, 3456, 4377600LL, 4423680LL);
    gub_kernel<<<108, blk, 0, stream>>>(gateb, upb, guB);

    gemm16_kernel<EPI_NONE, true><<<dim3(10,13), blk, 0, stream>>>(pix16, pw16, nullptr, nullptr, x, 1184, 1280, 1664);
    for (int i = 0; i < 4; ++i) {
        rms_kernel<<<1600, blk, 0, stream>>>(x, n1w + i*1280, h, 1280);
        gemm16_kernel<EPI_BIAS, false><<<dim3(30,13), blk, 0, stream>>>(h, qkvw16 + (size_t)i*4915200, qkvb + i*3840, nullptr, qbuf, 1280, 3840, 1664);
        rope_kernel<<<4000, blk, 0, stream>>>(qbuf, cosb, sinb);
        attn_kernel<<<dim3(25,16), blk, 0, stream>>>(qbuf, o);
        gemm16_kernel<EPI_BIAS_RESID, true><<<dim3(10,13), blk, 0, stream>>>(o, projw16 + (size_t)i*1638400, projb + i*1280, x, x, 1280, 1280, 1664);
        rms_kernel<<<1600, blk, 0, stream>>>(x, n2w + i*1280, h, 1280);
        gemm16_kernel<EPI_BIAS, false><<<dim3(54,13), blk, 0, stream>>>(h, guw16 + (size_t)i*8847360, guB + i*6912, nullptr, gu, 1280, 6912, 1664);
        silu_mul_kernel<<<2808, blk, 0, stream>>>(gu, gsep);
        gemm16_kernel<EPI_BIAS_RESID, true><<<dim3(10,13), blk, 0, stream>>>(gsep, downw16 + (size_t)i*4423680, downb + i*1280, x, x, 3456, 1280, 1664);
    }
    cvt_kernel<<<dim3(cvb(5120,5120),1), blk, 0, stream>>>(m1w, m1w16, 5120, 5120, 5120, 5120, 0, 0);
    cvt_kernel<<<dim3(cvb(3584,5120),1), blk, 0, stream>>>(m2w, m2w16, 3584, 5120, 3584, 5120, 0, 0);
    rms_kernel<<<1600, blk, 0, stream>>>(x, lnqw, h, 1280);
    gemm16_kernel<EPI_BIAS_GELU, false><<<dim3(40,4), blk, 0, stream>>>(h, m1w16, m1b, nullptr, t1, 5120, 5120, 512);
    gemm16_kernel<EPI_BIAS, true><<<dim3(28,4), blk, 0, stream>>>(t1, m2w16, m2b, nullptr, out, 5120, 3584, 400);
}

// Round 4
// 1770.129 us; speedup vs baseline: 3.1836x; 1.0170x over previous
//
#include <hip/hip_runtime.h>

// Qwen2.5-VL vision tower forward, MI355X gfx950 — round 3.
// Change vs r2: GEMM LDS bank-conflict fix (rule #21): linear global_load_lds
// dest + per-lane pre-swizzled GLOBAL source chunk + swizzled ds_read chunk.
// Chunk map: physical pc at row r holds logical pc ^ ((r>>1)&3)  -> the
// 16-lane b128 fragment read goes 8-way -> 2-way (free) on 32 banks.

typedef __bf16 bf16x8 __attribute__((ext_vector_type(8)));
typedef float  f32x4  __attribute__((ext_vector_type(4)));
typedef unsigned short u16;

#define DEV __device__ __forceinline__

DEV u16 f2bf(float f) {                       // RNE f32 -> bf16 bits
    union { float f; unsigned u; } v; v.f = f;
    unsigned r = v.u + 0x7FFFu + ((v.u >> 16) & 1u);
    return (u16)(r >> 16);
}
DEV float bf2f(u16 b) {
    union { float f; unsigned u; } v; v.u = ((unsigned)b) << 16; return v.f;
}

DEV void gload16(const u16* g, u16* l) {      // async global->LDS, 16B/lane
    __builtin_amdgcn_global_load_lds(
        (const __attribute__((address_space(1))) unsigned int*)g,
        (__attribute__((address_space(3))) unsigned int*)l, 16, 0, 0);
}

enum { EPI_NONE = 0, EPI_BIAS = 1, EPI_BIAS_RESID = 2, EPI_BIAS_GELU = 3 };

// f32 -> bf16 convert with zero-padding; blockIdx.y = layer.
__global__ void cvt_kernel(const float* __restrict__ src, u16* __restrict__ dst,
                           int Rs, int Cs, int Rp, int Cp,
                           long long sls, long long dls)
{
    const float* s = src + (size_t)blockIdx.y * sls;
    u16* d = dst + (size_t)blockIdx.y * dls;
    int idx = blockIdx.x * 256 + threadIdx.x;
    int cpc = Cp >> 3;
    if (idx >= Rp * cpc) return;
    int row = idx / cpc;
    int c0  = (idx - row * cpc) * 8;
    u16 v[8];
    if (row < Rs && c0 + 8 <= Cs) {
        float4 a = *reinterpret_cast<const float4*>(&s[(size_t)row * Cs + c0]);
        float4 b = *reinterpret_cast<const float4*>(&s[(size_t)row * Cs + c0 + 4]);
        v[0] = f2bf(a.x); v[1] = f2bf(a.y); v[2] = f2bf(a.z); v[3] = f2bf(a.w);
        v[4] = f2bf(b.x); v[5] = f2bf(b.y); v[6] = f2bf(b.z); v[7] = f2bf(b.w);
    } else {
#pragma unroll
        for (int j = 0; j < 8; ++j) {
            int c = c0 + j;
            v[j] = (row < Rs && c < Cs) ? f2bf(s[(size_t)row * Cs + c]) : (u16)0;
        }
    }
    *reinterpret_cast<uint4*>(&d[(size_t)row * Cp + c0]) =
        *reinterpret_cast<const uint4*>(v);
}

// Combined gate|up padded bias: [4][6912] f32.
__global__ void gub_kernel(const float* __restrict__ gb, const float* __restrict__ ub,
                           float* __restrict__ dst)
{
    int i = blockIdx.x * 256 + threadIdx.x;
    if (i >= 4 * 6912) return;
    int l = i / 6912, c = i - l * 6912;
    float v = 0.f;
    if (c < 3456) { if (c < 3420) v = gb[l * 3420 + c]; }
    else { int c2 = c - 3456; if (c2 < 3420) v = ub[l * 3420 + c2]; }
    dst[i] = v;
}

// out(RxC) = A(RxKp) @ B(CxKp)^T, bf16 in. Ring-3 LDS prefetch, counted vmcnt,
// chunk-XOR LDS swizzle (see header).
template <int EPI, bool OF32>
__global__ __launch_bounds__(256, 3)
void gemm16_kernel(const u16* __restrict__ A, const u16* __restrict__ B,
                   const float* __restrict__ bias, const float* __restrict__ resid,
                   void* __restrict__ outp, int Kp, int ldc, int Rlim)
{
    __shared__ u16 sA[3][4096];
    __shared__ u16 sB[3][4096];
    const int tid  = threadIdx.x;
    const int lane = tid & 63;
    const int w    = tid >> 6;

    // bijective XCD-chunked swizzle (m204), column-major linearization
    unsigned gy  = gridDim.y;
    unsigned nwg = gridDim.x * gy;
    unsigned lin = blockIdx.x * gy + blockIdx.y;
    unsigned q = nwg >> 3, r = nwg & 7, xc = lin & 7, off = lin >> 3;
    unsigned id2 = (xc < r ? xc * (q + 1) : r * (q + 1) + (xc - r) * q) + off;
    const int c0 = (int)(id2 / gy) * 128;
    const int r0 = (int)(id2 - (id2 / gy) * gy) * 128;

    const int wr  = (w >> 1) * 64;
    const int wc  = (w & 1) * 64;
    const int l15 = lane & 15;
    const int kk  = (lane >> 4) * 8;
    // per-lane read chunk: logical q=(lane>>4), physical q ^ ((row>>1)&3);
    // wr and f*16 drop out of (row>>1)&3, leaving (l15>>1)&3.
    const int pco = (((lane >> 4) ^ ((l15 >> 1) & 3)) * 8) - kk;  // addend to kk

    const int ca  = w * 128 + lane;                 // 16B-chunk id (ca, ca+64)
    const int cb  = ca + 64;
    // staging source chunk pre-swizzle: logical = (chunk&3) ^ ((chunk>>3)&3)
    const int sza = ((ca & 3) ^ ((ca >> 3) & 3)) * 8;
    const int szb = ((cb & 3) ^ ((cb >> 3) & 3)) * 8;
    const size_t arow0 = (size_t)(r0 + (ca >> 2)) * Kp + sza;
    const size_t brow0 = (size_t)(c0 + (ca >> 2)) * Kp + sza;
    const size_t arow1 = (size_t)(r0 + (cb >> 2)) * Kp + szb;
    const size_t brow1 = (size_t)(c0 + (cb >> 2)) * Kp + szb;

    f32x4 acc[4][4];
#pragma unroll
    for (int i = 0; i < 4; ++i)
#pragma unroll
        for (int j = 0; j < 4; ++j) acc[i][j] = (f32x4){0.f, 0.f, 0.f, 0.f};

    auto stage = [&](int kt, int buf) {
        int k0 = kt * 32;
        gload16(A + arow0 + k0, &sA[buf][ca * 8]);
        gload16(B + brow0 + k0, &sB[buf][ca * 8]);
        gload16(A + arow1 + k0, &sA[buf][cb * 8]);
        gload16(B + brow1 + k0, &sB[buf][cb * 8]);
    };
    auto compute = [&](int buf) {
        bf16x8 af[4], bfr[4];
#pragma unroll
        for (int f = 0; f < 4; ++f) {
            af[f]  = *reinterpret_cast<const bf16x8*>(&sA[buf][(wr + f * 16 + l15) * 32 + kk + pco]);
            bfr[f] = *reinterpret_cast<const bf16x8*>(&sB[buf][(wc + f * 16 + l15) * 32 + kk + pco]);
        }
#pragma unroll
        for (int fr = 0; fr < 4; ++fr)
#pragma unroll
            for (int fc = 0; fc < 4; ++fc)
                acc[fr][fc] = __builtin_amdgcn_mfma_f32_16x16x32_bf16(af[fr], bfr[fc], acc[fr][fc], 0, 0, 0);
    };

    const int NT = Kp >> 5;
    stage(0, 0);
    if (NT > 1) stage(1, 1);
    int bcur = 0;
    for (int t = 0; t < NT - 1; ++t) {
        asm volatile("s_waitcnt vmcnt(4)" ::: "memory");
        __builtin_amdgcn_s_barrier();
        __builtin_amdgcn_sched_barrier(0);
        if (t + 2 < NT) {
            int bn = bcur + 2; if (bn >= 3) bn -= 3;
            stage(t + 2, bn);
        }
        __builtin_amdgcn_sched_barrier(0);
        compute(bcur);
        bcur = (bcur == 2) ? 0 : bcur + 1;
    }
    asm volatile("s_waitcnt vmcnt(0)" ::: "memory");
    __builtin_amdgcn_s_barrier();
    __builtin_amdgcn_sched_barrier(0);
    compute(bcur);

    const int rowb = r0 + wr + (lane >> 4) * 4;
    const int colb = c0 + wc + l15;
#pragma unroll
    for (int fc = 0; fc < 4; ++fc) {
        int col = colb + fc * 16;
        float bv = (EPI != EPI_NONE) ? bias[col] : 0.f;
#pragma unroll
        for (int fr = 0; fr < 4; ++fr) {
#pragma unroll
            for (int r2 = 0; r2 < 4; ++r2) {
                int row = rowb + fr * 16 + r2;
                if (row >= Rlim) continue;
                float v = acc[fr][fc][r2] + bv;
                if (EPI == EPI_BIAS_RESID) v += resid[(size_t)row * ldc + col];
                if (EPI == EPI_BIAS_GELU)  v = 0.5f * v * (1.f + erff(v * 0.70710678118f));
                if (OF32) ((float*)outp)[(size_t)row * ldc + col] = v;
                else      ((u16*)outp)[(size_t)row * ldc + col] = f2bf(v);
            }
        }
    }
}

__global__ void rms_kernel(const float* __restrict__ x, const float* __restrict__ w,
                           u16* __restrict__ out, int cols)
{
    const int row = blockIdx.x;
    const int tid = threadIdx.x;
    const float* xr = x + (size_t)row * cols;
    float ss = 0.f;
    for (int c = tid; c < cols; c += 256) { float v = xr[c]; ss += v * v; }
#pragma unroll
    for (int m = 1; m < 64; m <<= 1) ss += __shfl_xor(ss, m);
    __shared__ float wsum[4];
    if ((tid & 63) == 0) wsum[tid >> 6] = ss;
    __syncthreads();
    float tot = wsum[0] + wsum[1] + wsum[2] + wsum[3];
    float rs = rsqrtf(tot / (float)cols + 1e-6f);
    u16* orow = out + (size_t)row * cols;
    for (int c = tid; c < cols; c += 256) orow[c] = f2bf(xr[c] * rs * w[c]);
}

// In-place RoPE on bf16 q,k halves of qkv.
__global__ void rope_kernel(u16* __restrict__ qkv, const float* __restrict__ cosb,
                            const float* __restrict__ sinb)
{
    int idx = blockIdx.x * 256 + threadIdx.x;   // < 1,024,000
    int n   = idx / 640;
    int rem = idx - n * 640;
    int hh  = rem / 40;
    int d   = rem - hh * 40;
    float c0 = cosb[n * 80 + d];
    float s0 = sinb[n * 80 + d];
    float c1 = cosb[n * 80 + d + 40];
    float s1 = sinb[n * 80 + d + 40];
    size_t base = (size_t)n * 3840 + hh * 80;
    float a = bf2f(qkv[base + d]), b = bf2f(qkv[base + d + 40]);
    qkv[base + d]      = f2bf(a * c0 - b * s0);
    qkv[base + d + 40] = f2bf(b * c1 + a * s1);
    base += 1280;
    a = bf2f(qkv[base + d]); b = bf2f(qkv[base + d + 40]);
    qkv[base + d]      = f2bf(a * c0 - b * s0);
    qkv[base + d + 40] = f2bf(b * c1 + a * s1);
}

// silu(gate)*up from fused [1664][6912] buffer -> packed [1664][3456].
__global__ void silu_mul_kernel(const u16* __restrict__ gu, u16* __restrict__ outb)
{
    int idx = blockIdx.x * 256 + threadIdx.x;
    if (idx >= 1664 * 432) return;
    int row = idx / 432, c8 = (idx - row * 432) * 8;
    u16 gv[8], uv[8];
    *reinterpret_cast<uint4*>(gv) = *reinterpret_cast<const uint4*>(&gu[(size_t)row * 6912 + c8]);
    *reinterpret_cast<uint4*>(uv) = *reinterpret_cast<const uint4*>(&gu[(size_t)row * 6912 + 3456 + c8]);
#pragma unroll
    for (int j = 0; j < 8; ++j) {
        float x = bf2f(gv[j]);
        gv[j] = f2bf(x / (1.f + expf(-x)) * bf2f(uv[j]));
    }
    *reinterpret_cast<uint4*>(&outb[(size_t)row * 3456 + c8]) = *reinterpret_cast<const uint4*>(gv);
}

// Flash attention on bf16 qkv (post-rope): 4 waves, 64 q-rows, 1 head/block.
__global__ __launch_bounds__(256, 2)
void attn_kernel(const u16* __restrict__ qkv, u16* __restrict__ o)
{
    __shared__ __align__(16) u16 Klds[64][104];
    __shared__ __align__(16) u16 Vt[80][72];
    __shared__ __align__(16) u16 Plds[4][16][72];
    const int tid  = threadIdx.x;
    const int lane = tid & 63;
    const int w    = tid >> 6;
    const int l15  = lane & 15;
    const int kk   = (lane >> 4) * 8;
    unsigned lin = blockIdx.y * 25 + blockIdx.x;       // nwg=400, 400%8==0
    unsigned id2 = (lin & 7) * 50 + (lin >> 3);
    const int hh = (int)(id2 / 25);
    const int qt = (int)(id2 - hh * 25);
    const float scale = 0.11180339887498949f;

    const int qrow = qt * 64 + w * 16 + l15;
    bf16x8 aq[3];
#pragma unroll
    for (int s = 0; s < 3; ++s) {
        int d = 32 * s + kk;
        union { bf16x8 v; uint4 q; } uu;
        if (d < 80) uu.q = *reinterpret_cast<const uint4*>(&qkv[(size_t)qrow * 3840 + hh * 80 + d]);
        else        uu.q = (uint4){0u, 0u, 0u, 0u};
        aq[s] = uu.v;
    }

    f32x4 acc_o[5];
#pragma unroll
    for (int fd = 0; fd < 5; ++fd) acc_o[fd] = (f32x4){0.f, 0.f, 0.f, 0.f};
    float m[4], lsum[4];
#pragma unroll
    for (int r2 = 0; r2 < 4; ++r2) { m[r2] = -__builtin_inff(); lsum[r2] = 0.f; }

    const int koff = 1280 + hh * 80;
    const int voff = 2560 + hh * 80;

    for (int kb = 0; kb < 25; ++kb) {
#pragma unroll
        for (int i = 0; i < 3; ++i) {             // K tile: 64 rows x 12 chunks
            int c = tid + 256 * i;                // 0..767
            int r = c / 12, c8 = (c - r * 12) * 8;
            uint4 pk = (uint4){0u, 0u, 0u, 0u};
            if (c8 < 80)
                pk = *reinterpret_cast<const uint4*>(&qkv[(size_t)(kb * 64 + r) * 3840 + koff + c8]);
            *reinterpret_cast<uint4*>(&Klds[r][c8]) = pk;
        }
#pragma unroll
        for (int i = 0; i < 3; ++i) {             // V tile transposed: 640 chunks
            int c = tid + 256 * i;
            if (c < 640) {
                int r = c / 10, c8 = (c - r * 10) * 8;
                u16 v[8];
                *reinterpret_cast<uint4*>(v) =
                    *reinterpret_cast<const uint4*>(&qkv[(size_t)(kb * 64 + r) * 3840 + voff + c8]);
#pragma unroll
                for (int j = 0; j < 8; ++j) Vt[c8 + j][r] = v[j];
            }
        }
        __syncthreads();

        f32x4 sf[4];
#pragma unroll
        for (int fc = 0; fc < 4; ++fc) {
            f32x4 c = (f32x4){0.f, 0.f, 0.f, 0.f};
#pragma unroll
            for (int s = 0; s < 3; ++s)
                c = __builtin_amdgcn_mfma_f32_16x16x32_bf16(
                        aq[s],
                        *reinterpret_cast<const bf16x8*>(&Klds[fc * 16 + l15][32 * s + kk]),
                        c, 0, 0, 0);
            sf[fc] = c * scale;
        }

        float mx[4];
#pragma unroll
        for (int r2 = 0; r2 < 4; ++r2)
            mx[r2] = fmaxf(fmaxf(sf[0][r2], sf[1][r2]), fmaxf(sf[2][r2], sf[3][r2]));
#pragma unroll
        for (int msk = 1; msk <= 8; msk <<= 1)
#pragma unroll
            for (int r2 = 0; r2 < 4; ++r2)
                mx[r2] = fmaxf(mx[r2], __shfl_xor(mx[r2], msk));
        float alpha[4];
#pragma unroll
        for (int r2 = 0; r2 < 4; ++r2) {
            float mn = fmaxf(m[r2], mx[r2]);
            alpha[r2] = expf(m[r2] - mn);
            m[r2] = mn;
        }
        float psum[4] = {0.f, 0.f, 0.f, 0.f};
#pragma unroll
        for (int fc = 0; fc < 4; ++fc)
#pragma unroll
            for (int r2 = 0; r2 < 4; ++r2) {
                float p = expf(sf[fc][r2] - m[r2]);
                sf[fc][r2] = p;
                psum[r2] += p;
            }
#pragma unroll
        for (int msk = 1; msk <= 8; msk <<= 1)
#pragma unroll
            for (int r2 = 0; r2 < 4; ++r2) psum[r2] += __shfl_xor(psum[r2], msk);
#pragma unroll
        for (int r2 = 0; r2 < 4; ++r2) lsum[r2] = lsum[r2] * alpha[r2] + psum[r2];
#pragma unroll
        for (int fd = 0; fd < 5; ++fd)
#pragma unroll
            for (int r2 = 0; r2 < 4; ++r2) acc_o[fd][r2] *= alpha[r2];

        const int prow = (lane >> 4) * 4;
#pragma unroll
        for (int fc = 0; fc < 4; ++fc)
#pragma unroll
            for (int r2 = 0; r2 < 4; ++r2)
                Plds[w][prow + r2][fc * 16 + l15] = f2bf(sf[fc][r2]);

        bf16x8 ap[2];
#pragma unroll
        for (int ks = 0; ks < 2; ++ks)
            ap[ks] = *reinterpret_cast<const bf16x8*>(&Plds[w][l15][32 * ks + kk]);
#pragma unroll
        for (int fd = 0; fd < 5; ++fd)
#pragma unroll
            for (int ks = 0; ks < 2; ++ks)
                acc_o[fd] = __builtin_amdgcn_mfma_f32_16x16x32_bf16(
                        ap[ks],
                        *reinterpret_cast<const bf16x8*>(&Vt[fd * 16 + l15][32 * ks + kk]),
                        acc_o[fd], 0, 0, 0);
        __syncthreads();
    }

    float inv[4];
#pragma unroll
    for (int r2 = 0; r2 < 4; ++r2) inv[r2] = 1.f / lsum[r2];
    const int orow = qt * 64 + w * 16 + (lane >> 4) * 4;
    const int ocol = hh * 80 + l15;
#pragma unroll
    for (int fd = 0; fd < 5; ++fd)
#pragma unroll
        for (int r2 = 0; r2 < 4; ++r2)
            o[(size_t)(orow + r2) * 1280 + ocol + fd * 16] = f2bf(acc_o[fd][r2] * inv[r2]);
}

extern "C" void kernel_launch(void* const* d_in, const int* in_sizes, int n_in,
                              void* d_out, int out_size, void* d_ws, size_t ws_size,
                              hipStream_t stream)
{
    const float* pixel  = (const float*)d_in[0];
    const float* cosb   = (const float*)d_in[1];
    const float* sinb   = (const float*)d_in[2];
    const float* patchw = (const float*)d_in[3];
    const float* n1w    = (const float*)d_in[4];
    const float* qkvw   = (const float*)d_in[5];
    const float* qkvb   = (const float*)d_in[6];
    const float* projw  = (const float*)d_in[7];
    const float* projb  = (const float*)d_in[8];
    const float* n2w    = (const float*)d_in[9];
    const float* gatew  = (const float*)d_in[10];
    const float* gateb  = (const float*)d_in[11];
    const float* upw    = (const float*)d_in[12];
    const float* upb    = (const float*)d_in[13];
    const float* downw  = (const float*)d_in[14];
    const float* downb  = (const float*)d_in[15];
    const float* lnqw   = (const float*)d_in[16];
    const float* m1w    = (const float*)d_in[17];
    const float* m1b    = (const float*)d_in[18];
    const float* m2w    = (const float*)d_in[19];
    const float* m2b    = (const float*)d_in[20];
    float* out = (float*)d_out;

    char* base = (char*)d_ws;
    float* x      = (float*)(base);                       //  1664x1280 f32
    u16*   h      = (u16*)(base + 8519680);               //  1664x1280
    u16*   qbuf   = (u16*)(base + 12779520);              //  1664x3840
    u16*   pix16  = qbuf;                                 //  alias (pre-loop)
    u16*   gsep   = (u16*)(base + 25559040);              //  1664x3456
    u16*   o      = gsep;                                 //  alias (attn->proj)
    u16*   pw16   = gsep;                                 //  alias (pre-loop)
    u16*   gu     = (u16*)(base + 37060608);              //  1664x6912
    u16*   t1     = gu;                                   //  alias (post-loop, 512x5120)
    float* guB    = (float*)(base + 60063744);            //  4x6912 f32
    u16*   qkvw16 = (u16*)(base + 60174336);              //  4x3840x1280
    u16*   projw16= (u16*)(base + 99495936);              //  4x1280x1280
    u16*   guw16  = (u16*)(base + 112603136);             //  4x6912x1280
    u16*   downw16= (u16*)(base + 183382016);             //  4x1280x3456 (end 218.8MB)
    u16*   m1w16  = guw16;                                //  alias (post-loop)
    u16*   m2w16  = (u16*)(base + 112603136 + 52428800);  //  alias (post-loop)

    dim3 blk(256);
    auto cvb = [](int Rp, int Cp) { return (Rp * (Cp >> 3) + 255) / 256; };

    cvt_kernel<<<dim3(cvb(1664,1184),1), blk, 0, stream>>>(pixel, pix16, 1600, 1176, 1664, 1184, 0, 0);
    cvt_kernel<<<dim3(cvb(1280,1184),1), blk, 0, stream>>>(patchw, pw16, 1280, 1176, 1280, 1184, 0, 0);
    cvt_kernel<<<dim3(cvb(15360,1280),1), blk, 0, stream>>>(qkvw, qkvw16, 15360, 1280, 15360, 1280, 0, 0);
    cvt_kernel<<<dim3(cvb(5120,1280),1), blk, 0, stream>>>(projw, projw16, 5120, 1280, 5120, 1280, 0, 0);
    cvt_kernel<<<dim3(cvb(3456,1280),4), blk, 0, stream>>>(gatew, guw16, 3420, 1280, 3456, 1280, 4377600LL, 8847360LL);
    cvt_kernel<<<dim3(cvb(3456,1280),4), blk, 0, stream>>>(upw, guw16 + 4423680, 3420, 1280, 3456, 1280, 4377600LL, 8847360LL);
    cvt_kernel<<<dim3(cvb(1280,3456),4), blk, 0, stream>>>(downw, downw16, 1280, 3420, 1280, 3456, 4377600LL, 4423680LL);
    gub_kernel<<<108, blk, 0, stream>>>(gateb, upb, guB);

    gemm16_kernel<EPI_NONE, true><<<dim3(10,13), blk, 0, stream>>>(pix16, pw16, nullptr, nullptr, x, 1184, 1280, 1664);
    for (int i = 0; i < 4; ++i) {
        rms_kernel<<<1600, blk, 0, stream>>>(x, n1w + i*1280, h, 1280);
        gemm16_kernel<EPI_BIAS, false><<<dim3(30,13), blk, 0, stream>>>(h, qkvw16 + (size_t)i*4915200, qkvb + i*3840, nullptr, qbuf, 1280, 3840, 1664);
        rope_kernel<<<4000, blk, 0, stream>>>(qbuf, cosb, sinb);
        attn_kernel<<<dim3(25,16), blk, 0, stream>>>(qbuf, o);
        gemm16_kernel<EPI_BIAS_RESID, true><<<dim3(10,13), blk, 0, stream>>>(o, projw16 + (size_t)i*1638400, projb + i*1280, x, x, 1280, 1280, 1664);
        rms_kernel<<<1600, blk, 0, stream>>>(x, n2w + i*1280, h, 1280);
        gemm16_kernel<EPI_BIAS, false><<<dim3(54,13), blk, 0, stream>>>(h, guw16 + (size_t)i*8847360, guB + i*6912, nullptr, gu, 1280, 6912, 1664);
        silu_mul_kernel<<<2808, blk, 0, stream>>>(gu, gsep);
        gemm16_kernel<EPI_BIAS_RESID, true><<<dim3(10,13), blk, 0, stream>>>(gsep, downw16 + (size_t)i*4423680, downb + i*1280, x, x, 3456, 1280, 1664);
    }
    cvt_kernel<<<dim3(cvb(5120,5120),1), blk, 0, stream>>>(m1w, m1w16, 5120, 5120, 5120, 5120, 0, 0);
    cvt_kernel<<<dim3(cvb(3584,5120),1), blk, 0, stream>>>(m2w, m2w16, 3584, 5120, 3584, 5120, 0, 0);
    rms_kernel<<<1600, blk, 0, stream>>>(x, lnqw, h, 1280);
    gemm16_kernel<EPI_BIAS_GELU, false><<<dim3(40,4), blk, 0, stream>>>(h, m1w16, m1b, nullptr, t1, 5120, 5120, 512);
    gemm16_kernel<EPI_BIAS, true><<<dim3(28,4), blk, 0, stream>>>(t1, m2w16, m2b, nullptr, out, 5120, 3584, 400);
}